// Round 3
// baseline (198.634 us; speedup 1.0000x reference)
//
#include <hip/hip_runtime.h>

// Pairlist: 2000 molecules x 64 atoms, ordered intra-molecule pairs.
// Out (flat f32): i[P], j[P], d[P], r_ij[P*3]; P = 8,064,000. Write-bound.
// R3: ALL global stores issued after the last __syncthreads (compiler emits
// s_waitcnt vmcnt(0) before s_barrier -> R2 drained i/j/d stores mid-kernel).
// Also nontemporal stores: 193.5 MB never re-read, skip L2 allocation.

#define N_MOL   2000
#define MOL_A   64
#define PPM     (MOL_A * (MOL_A - 1))    // 4032 pairs / molecule
#define P_TOTAL (N_MOL * PPM)            // 8,064,000
#define BLOCK   256
#define PPB     1024                     // pairs per block (4 per thread)
#define POS_W   384                      // 2 molecules * 64 atoms * 3 words
#define RSTRIDE 13                       // 12 data + 1 pad (stride 13 vs 32
                                         // banks -> 2-way alias = free)

typedef float f4 __attribute__((ext_vector_type(4)));

__global__ __launch_bounds__(BLOCK) void Pairlist_54932631716418_kernel(
    const float* __restrict__ pos, float* __restrict__ out) {
  __shared__ float posb[POS_W];            // 1.5 KB
  __shared__ float rbuf[BLOCK * RSTRIDE];  // 13 KB

  const int t  = threadIdx.x;
  const int P0 = blockIdx.x * PPB;
  const int mf = P0 / PPM;                 // first molecule this block touches

  // ---- stage up to 2 molecules of positions (flat, clamped) ----
  {
    const int gmax = N_MOL * MOL_A * 3 - 1;
    int g0 = mf * (MOL_A * 3);
    int a0 = g0 + t;       if (a0 > gmax) a0 = gmax;
    posb[t] = pos[a0];
    if (t + BLOCK < POS_W) {
      int a1 = g0 + t + BLOCK; if (a1 > gmax) a1 = gmax;
      posb[t + BLOCK] = pos[a1];
    }
  }
  __syncthreads();

  // ---- compute 4 consecutive pairs (4032 % 4 == 0: one molecule/thread) ----
  const int p0 = P0 + 4 * t;
  int rp     = p0 - mf * PPM;
  int molOff = 0;
  int base   = mf * MOL_A;
  if (rp >= PPM) { rp -= PPM; molOff = MOL_A * 3; base += MOL_A; }

  float fi[4], fj[4], fd[4];
#pragma unroll
  for (int s = 0; s < 4; ++s) {
    const int r = rp + s;
    const int i = r / 63;                  // magic-mul
    const int k = r - 63 * i;
    const int j = k + (k >= i ? 1 : 0);
    const float xi = posb[molOff + 3 * i + 0];
    const float yi = posb[molOff + 3 * i + 1];
    const float zi = posb[molOff + 3 * i + 2];
    const float xj = posb[molOff + 3 * j + 0];
    const float yj = posb[molOff + 3 * j + 1];
    const float zj = posb[molOff + 3 * j + 2];
    const float rx = xj - xi, ry = yj - yi, rz = zj - zi;
    fi[s] = (float)(base + i);
    fj[s] = (float)(base + j);
    fd[s] = sqrtf(rx * rx + ry * ry + rz * rz);
    rbuf[RSTRIDE * t + 3 * s + 0] = rx;    // LDS only — no global stores yet
    rbuf[RSTRIDE * t + 3 * s + 1] = ry;
    rbuf[RSTRIDE * t + 3 * s + 2] = rz;
  }

  __syncthreads();   // drains only lgkmcnt (no global stores outstanding)

  // ---- gather r_ij float4s from padded transpose buffer ----
  // compact float F lives at LDS word RSTRIDE*(F/12) + F%12; out float4 g
  // covers F = 4g..4g+3 with F/12 = g/3, F%12 = 4*(g%3)+q.
  f4 rv[3];
#pragma unroll
  for (int s = 0; s < 3; ++s) {
    const int g = t + s * BLOCK;
    const int a = g / 3;                   // magic-mul
    const int b = g - 3 * a;
    const int w = RSTRIDE * a + 4 * b;
    rv[s] = (f4){rbuf[w], rbuf[w + 1], rbuf[w + 2], rbuf[w + 3]};
  }

  // ---- ALL global stores last, nontemporal, no barrier after ----
  f4 vi = (f4){fi[0], fi[1], fi[2], fi[3]};
  f4 vj = (f4){fj[0], fj[1], fj[2], fj[3]};
  f4 vd = (f4){fd[0], fd[1], fd[2], fd[3]};
  __builtin_nontemporal_store(vi, (f4*)(out + p0));
  __builtin_nontemporal_store(vj, (f4*)(out + P_TOTAL + p0));
  __builtin_nontemporal_store(vd, (f4*)(out + 2 * P_TOTAL + p0));
  float* outr = out + 3 * (size_t)P_TOTAL + 3 * (size_t)P0;
#pragma unroll
  for (int s = 0; s < 3; ++s) {
    __builtin_nontemporal_store(rv[s], (f4*)(outr + 4 * (t + s * BLOCK)));
  }
}

extern "C" void kernel_launch(void* const* d_in, const int* in_sizes, int n_in,
                              void* d_out, int out_size, void* d_ws, size_t ws_size,
                              hipStream_t stream) {
  const float* pos = (const float*)d_in[0];   // positions [128000, 3] f32
  float* out = (float*)d_out;
  const int blocks = P_TOTAL / PPB;           // 7875 exact
  Pairlist_54932631716418_kernel<<<blocks, BLOCK, 0, stream>>>(pos, out);
}

// Round 4
// 197.954 us; speedup vs baseline: 1.0034x; 1.0034x over previous
//
#include <hip/hip_runtime.h>

// Pairlist: 2000 molecules x 64 atoms, ordered intra-molecule pairs.
// Out (flat f32): i[P], j[P], d[P], r_ij[P*3]; P = 8,064,000. Write-bound.
// R4: wave-local r-transpose (no 2nd barrier; waves fully independent after
// the posb stage), padded 4-word atoms -> ds_read_b128 position reads,
// SoA rbuf -> ds_write_b128. Stores last + nontemporal.

#define N_MOL   2000
#define MOL_A   64
#define PPM     (MOL_A * (MOL_A - 1))    // 4032 pairs / molecule
#define P_TOTAL (N_MOL * PPM)            // 8,064,000
#define BLOCK   256
#define PPB     1024                     // pairs per block (4 per thread)

typedef float f4 __attribute__((ext_vector_type(4)));

__global__ __launch_bounds__(BLOCK) void Pairlist_54932631716418_kernel(
    const float* __restrict__ pos, float* __restrict__ out) {
  __shared__ float posb[128 * 4];          // 2 molecules, 4 words/atom (2 KB)
  __shared__ float rbuf[4][3][256];        // per-wave SoA rx/ry/rz (12 KB)

  const int t  = threadIdx.x;
  const int L  = t & 63;                   // lane
  const int w  = t >> 6;                   // wave id in block
  const int P0 = blockIdx.x * PPB;
  const int mf = P0 / PPM;                 // first molecule this block touches

  // ---- stage 2 molecules, padded to 4 words/atom ----
  {
    const int gmax = N_MOL * MOL_A * 3 - 1;
    const int g0   = mf * (MOL_A * 3);
    int v = t;                             // source word 0..383
    int a = g0 + v; if (a > gmax) a = gmax;
    float x = pos[a];
    if (v < 384) posb[(v / 3) * 4 + (v - (v / 3) * 3)] = x;
    v = t + BLOCK;
    if (v < 384) {
      int a1 = g0 + v; if (a1 > gmax) a1 = gmax;
      float x1 = pos[a1];
      posb[(v / 3) * 4 + (v - (v / 3) * 3)] = x1;
    }
  }
  __syncthreads();                         // only barrier (no stores pending)

  // ---- 4 consecutive pairs per thread (4032 % 4 == 0: single molecule) ----
  const int p0 = P0 + 4 * t;
  int rp      = p0 - mf * PPM;
  int atomOff = 0;
  int base    = mf * MOL_A;
  if (rp >= PPM) { rp -= PPM; atomOff = 64; base += MOL_A; }

  float fi[4], fj[4], fd[4];
  f4 rx, ry, rz;
#pragma unroll
  for (int s = 0; s < 4; ++s) {
    const int r = rp + s;
    const int i = r / 63;                  // magic-mul
    const int k = r - 63 * i;
    const int j = k + (k >= i ? 1 : 0);
    const f4 pi = *(const f4*)(posb + 4 * (atomOff + i));  // ds_read_b128
    const f4 pj = *(const f4*)(posb + 4 * (atomOff + j));  // ds_read_b128
    const float dx = pj.x - pi.x, dy = pj.y - pi.y, dz = pj.z - pi.z;
    fi[s] = (float)(base + i);
    fj[s] = (float)(base + j);
    fd[s] = sqrtf(dx * dx + dy * dy + dz * dz);
    ((float*)&rx)[s] = dx; ((float*)&ry)[s] = dy; ((float*)&rz)[s] = dz;
  }

  // ---- wave-local SoA staging: 3x ds_write_b128, no barrier needed ----
  *(f4*)&rbuf[w][0][4 * L] = rx;
  *(f4*)&rbuf[w][1][4 * L] = ry;
  *(f4*)&rbuf[w][2][4 * L] = rz;

  // ---- gather this wave's lane-contiguous r float4s (wave-local RAW:
  //      in-order DS pipe + compiler lgkmcnt wait; no __syncthreads) ----
  const float* rb = &rbuf[w][0][0];
  f4 rv[3];
#pragma unroll
  for (int s = 0; s < 3; ++s) {
#pragma unroll
    for (int u = 0; u < 4; ++u) {
      const int F = 256 * s + 4 * L + u;   // wave-local r-stream float index
      const int q = F / 3;                 // magic-mul
      const int c = F - 3 * q;
      ((float*)&rv[s])[u] = rb[256 * c + q];
    }
  }

  // ---- all global stores last, nontemporal ----
  __builtin_nontemporal_store((f4){fi[0], fi[1], fi[2], fi[3]}, (f4*)(out + p0));
  __builtin_nontemporal_store((f4){fj[0], fj[1], fj[2], fj[3]}, (f4*)(out + P_TOTAL + p0));
  __builtin_nontemporal_store((f4){fd[0], fd[1], fd[2], fd[3]}, (f4*)(out + 2 * P_TOTAL + p0));
  // wave-local output f4 index: 768*b + 192*w + 64*s + L (lane-contiguous)
  float* outr = out + 3 * (size_t)P_TOTAL + 12 * (size_t)P0 / 4;
#pragma unroll
  for (int s = 0; s < 3; ++s) {
    const int g = 192 * w + 64 * s + L;
    __builtin_nontemporal_store(rv[s], (f4*)(outr + 4 * g));
  }
}

extern "C" void kernel_launch(void* const* d_in, const int* in_sizes, int n_in,
                              void* d_out, int out_size, void* d_ws, size_t ws_size,
                              hipStream_t stream) {
  const float* pos = (const float*)d_in[0];   // positions [128000, 3] f32
  float* out = (float*)d_out;
  const int blocks = P_TOTAL / PPB;           // 7875 exact
  Pairlist_54932631716418_kernel<<<blocks, BLOCK, 0, stream>>>(pos, out);
}